// Round 4
// baseline (109.588 us; speedup 1.0000x reference)
//
#include <hip/hip_runtime.h>

typedef __bf16 bf16_t;
typedef __bf16 bf16x8 __attribute__((ext_vector_type(8)));
typedef float f32x4 __attribute__((ext_vector_type(4)));

#define GK 768   // inner K dim for every GEMM in this problem

// ---------------- workspace layout (bytes) ----------------
static constexpr size_t OFF_WT_QKV = 0;                                  // [2304][768] bf16
static constexpr size_t OFF_WT_CAR  = OFF_WT_QKV + (size_t)2304*768*2;   // [768][768] bf16
static constexpr size_t OFF_WT_PROJ = OFF_WT_CAR + (size_t)768*768*2;    // [768][768] bf16
static constexpr size_t OFF_WMEAN   = OFF_WT_PROJ + (size_t)768*768*2;   // [256][768] bf16
static constexpr size_t OFF_CARP    = OFF_WMEAN + (size_t)256*768*2;     // [4][256][768] f32 split-K partials
static constexpr size_t OFF_LN      = OFF_CARP + (size_t)4*256*768*4;    // [5120][768] bf16
static constexpr size_t OFF_QKV     = OFF_LN + (size_t)5120*768*2;       // [5120][2304] bf16 (q|k|v)
static constexpr size_t OFF_CTX     = OFF_QKV + (size_t)5120*2304*2;     // [2][2048][768] bf16

// ---------------- async global->LDS (16B per lane) ----------------
__device__ __forceinline__ void gload16(const bf16_t* g, bf16_t* lds_wave_base) {
  __builtin_amdgcn_global_load_lds(
      (const __attribute__((address_space(1))) unsigned int*)g,
      (__attribute__((address_space(3))) unsigned int*)lds_wave_base,
      16, 0, 0);
}

// ---------------- fused prep: 3 weight transposes (fp32->bf16, W[K][N]->Wt[N][K]) + window means ----------------
__global__ __launch_bounds__(256) void prep_kernel(const float* __restrict__ W_qkv,
                                                   const float* __restrict__ W_car,
                                                   const float* __restrict__ W_proj,
                                                   const float* __restrict__ x,
                                                   bf16_t* __restrict__ wt_qkv,
                                                   bf16_t* __restrict__ wt_car,
                                                   bf16_t* __restrict__ wt_proj,
                                                   bf16_t* __restrict__ wm) {
  int bid = blockIdx.x;
  if (bid < 2880) {
    __shared__ float tile[32][33];
    const float* W; bf16_t* Wt; int Ndim, kb, nb;
    if (bid < 1728) {
      W = W_qkv; Wt = wt_qkv; Ndim = 2304; kb = (bid % 24) * 32; nb = (bid / 24) * 32;
    } else if (bid < 2304) {
      int q = bid - 1728; W = W_car; Wt = wt_car; Ndim = 768; kb = (q % 24) * 32; nb = (q / 24) * 32;
    } else {
      int q = bid - 2304; W = W_proj; Wt = wt_proj; Ndim = 768; kb = (q % 24) * 32; nb = (q / 24) * 32;
    }
    int tx = threadIdx.x & 31, ty = threadIdx.x >> 5;   // ty in 0..7
    #pragma unroll
    for (int i = 0; i < 32; i += 8)
      tile[ty + i][tx] = W[(size_t)(kb + ty + i) * Ndim + nb + tx];
    __syncthreads();
    #pragma unroll
    for (int i = 0; i < 32; i += 8)
      Wt[(size_t)(nb + ty + i) * GK + kb + tx] = (bf16_t)tile[tx][ty + i];
  } else {
    int w = bid - 2880;            // 0..255  (b*128 + window)
    int b = w >> 7, ww = w & 127;
    const float* base = x + ((size_t)b * 2048 + (size_t)ww * 16) * 768;
    for (int d = threadIdx.x; d < 768; d += 256) {
      float s = 0.f;
      #pragma unroll
      for (int i = 0; i < 16; i++) s += base[(size_t)i * 768 + d];
      wm[(size_t)w * 768 + d] = (bf16_t)(s * (1.f / 16.f));
    }
  }
}

// ---------------- 64x128-tile bf16 MFMA GEMM with optional split-K ----------------
// mode 0: car partials -> outF[kz][row][col] (no bias)
// mode 2: proj -> outF[row][col] = acc + bias
__global__ __launch_bounds__(256) void gemm64_kernel(const bf16_t* __restrict__ A,
                                                     const bf16_t* __restrict__ Bt,
                                                     const float* __restrict__ bias,
                                                     float* __restrict__ outF,
                                                     int mB, int nB, int kspan, int mode) {
  __shared__ __align__(16) bf16_t As[64 * 32];
  __shared__ __align__(16) bf16_t Bs[128 * 32];
  int bid = blockIdx.x;
  int bm = bid % mB;
  int rest = bid / mB;
  int bn = rest % nB;
  int kz = rest / nB;
  int t = threadIdx.x, wid = t >> 6, lane = t & 63;
  int wm = wid >> 1, wn = wid & 1;
  int sr = t >> 2, sk = (t & 3) * 8;
  const bf16_t* gA = A + (size_t)(bm * 64 + sr) * GK + sk;
  const bf16_t* gB = Bt + (size_t)(bn * 128 + sr) * GK + sk;
  bf16_t* lA  = As + wid * 512;
  bf16_t* lB0 = Bs + wid * 512;
  bf16_t* lB1 = Bs + 2048 + wid * 512;
  int fr = lane & 15, fk = (lane >> 4) * 8;

  f32x4 acc[2][4] = {};
  int k0 = kz * kspan, kend = k0 + kspan;
  for (; k0 < kend; k0 += 32) {
    gload16(gA + k0,           lA);
    gload16(gB + k0,           lB0);
    gload16(gB + k0 + 64 * GK, lB1);
    __syncthreads();
    bf16x8 af[2], bfr[4];
    #pragma unroll
    for (int i = 0; i < 2; i++)
      af[i] = *(const bf16x8*)(As + (wm * 32 + i * 16 + fr) * 32 + fk);
    #pragma unroll
    for (int j = 0; j < 4; j++)
      bfr[j] = *(const bf16x8*)(Bs + (wn * 64 + j * 16 + fr) * 32 + fk);
    #pragma unroll
    for (int i = 0; i < 2; i++)
      #pragma unroll
      for (int j = 0; j < 4; j++)
        acc[i][j] = __builtin_amdgcn_mfma_f32_16x16x32_bf16(af[i], bfr[j], acc[i][j], 0, 0, 0);
    __syncthreads();
  }

  #pragma unroll
  for (int i = 0; i < 2; i++) {
    int rbase = bm * 64 + wm * 32 + i * 16 + ((lane >> 4) << 2);
    #pragma unroll
    for (int j = 0; j < 4; j++) {
      int col = bn * 128 + wn * 64 + j * 16 + (lane & 15);
      f32x4 a = acc[i][j];
      float bcol = (mode == 2) ? bias[col] : 0.f;
      #pragma unroll
      for (int r = 0; r < 4; r++) {
        int row = rbase + r;
        if (mode == 0)
          outF[(size_t)kz * 196608 + (size_t)row * 768 + col] = a[r];
        else
          outF[(size_t)row * 768 + col] = a[r] + bcol;
      }
    }
  }
}

// ---------------- fused LayerNorm over "combined" rows -> bf16 ----------------
__global__ __launch_bounds__(256) void ln_kernel(const float* __restrict__ x,
                                                 const float* __restrict__ carP,
                                                 const float* __restrict__ b_car,
                                                 const float* __restrict__ gamma,
                                                 const float* __restrict__ beta,
                                                 bf16_t* __restrict__ out) {
  __shared__ float red[8];
  int row = blockIdx.x;                 // 0 .. 5119
  int b = row / 2560, n = row - b * 2560;
  int t = threadIdx.x;
  float v0, v1, v2;
  if (n < 2048) {
    const float* src = x + ((size_t)b * 2048 + n) * 768;
    v0 = src[t]; v1 = src[t + 256]; v2 = src[t + 512];
  } else {
    size_t ci = (size_t)(b * 128 + ((n - 2048) >> 2)) * 768;
    const float* p0 = carP + ci;
    const float* p1 = carP + ci + 196608;
    const float* p2 = carP + ci + 2 * 196608;
    const float* p3 = carP + ci + 3 * 196608;
    v0 = p0[t]       + p1[t]       + p2[t]       + p3[t]       + b_car[t];
    v1 = p0[t + 256] + p1[t + 256] + p2[t + 256] + p3[t + 256] + b_car[t + 256];
    v2 = p0[t + 512] + p1[t + 512] + p2[t + 512] + p3[t + 512] + b_car[t + 512];
  }
  float s = v0 + v1 + v2;
  float q = v0 * v0 + v1 * v1 + v2 * v2;
  #pragma unroll
  for (int o = 32; o > 0; o >>= 1) { s += __shfl_down(s, o); q += __shfl_down(q, o); }
  int wv = t >> 6;
  if ((t & 63) == 0) { red[wv] = s; red[4 + wv] = q; }
  __syncthreads();
  s = red[0] + red[1] + red[2] + red[3];
  q = red[4] + red[5] + red[6] + red[7];
  float mean = s * (1.f / 768.f);
  float var  = q * (1.f / 768.f) - mean * mean;
  float rstd = rsqrtf(var + 1e-5f);
  bf16_t* o0 = out + (size_t)row * 768;
  o0[t]       = (bf16_t)((v0 - mean) * rstd * gamma[t]       + beta[t]);
  o0[t + 256] = (bf16_t)((v1 - mean) * rstd * gamma[t + 256] + beta[t + 256]);
  o0[t + 512] = (bf16_t)((v2 - mean) * rstd * gamma[t + 512] + beta[t + 512]);
}

// ---------------- 128x128 bf16 MFMA GEMM -> plain [5120][2304] bf16 (q cols pre-scaled) ----------------
__global__ __launch_bounds__(256) void gemm_qkv(const bf16_t* __restrict__ A,
                                                const bf16_t* __restrict__ Bt,
                                                const float* __restrict__ bias,
                                                bf16_t* __restrict__ qkv,
                                                int mBlocks) {
  __shared__ __align__(16) bf16_t As[128 * 32];
  __shared__ __align__(16) bf16_t Bs[128 * 32];

  int bm = blockIdx.x % mBlocks;
  int bn = blockIdx.x / mBlocks;
  int t = threadIdx.x;
  int wid = t >> 6, lane = t & 63;
  int wm = wid >> 1, wn = wid & 1;

  int sr = t >> 2;
  int sk = (t & 3) * 8;
  const bf16_t* gA = A + ((size_t)(bm * 128 + sr)) * GK + sk;
  const bf16_t* gB = Bt + ((size_t)(bn * 128 + sr)) * GK + sk;
  bf16_t* lA0 = As + wid * 512;
  bf16_t* lA1 = As + 2048 + wid * 512;
  bf16_t* lB0 = Bs + wid * 512;
  bf16_t* lB1 = Bs + 2048 + wid * 512;

  int fr = lane & 15;
  int fk = (lane >> 4) * 8;

  f32x4 acc[4][4] = {};

  for (int k0 = 0; k0 < GK; k0 += 32) {
    gload16(gA + k0,            lA0);
    gload16(gA + k0 + 64 * GK,  lA1);
    gload16(gB + k0,            lB0);
    gload16(gB + k0 + 64 * GK,  lB1);
    __syncthreads();
    bf16x8 af[4], bfr[4];
    #pragma unroll
    for (int i = 0; i < 4; i++)
      af[i] = *(const bf16x8*)(As + (wm * 64 + i * 16 + fr) * 32 + fk);
    #pragma unroll
    for (int i = 0; i < 4; i++)
      bfr[i] = *(const bf16x8*)(Bs + (wn * 64 + i * 16 + fr) * 32 + fk);
    #pragma unroll
    for (int i = 0; i < 4; i++)
      #pragma unroll
      for (int j = 0; j < 4; j++)
        acc[i][j] = __builtin_amdgcn_mfma_f32_16x16x32_bf16(af[i], bfr[j], acc[i][j], 0, 0, 0);
    __syncthreads();
  }

  // epilogue: D layout col = lane&15, row = (lane>>4)*4 + reg; plain row-major store
  #pragma unroll
  for (int i = 0; i < 4; i++) {
    int rbase = bm * 128 + wm * 64 + i * 16 + ((lane >> 4) << 2);
    #pragma unroll
    for (int j = 0; j < 4; j++) {
      int col = bn * 128 + wn * 64 + j * 16 + (lane & 15);
      float bcol = bias[col];
      float sc = (col < 768) ? 0.125f : 1.f;   // fold SCALE into q section
      f32x4 a = acc[i][j];
      #pragma unroll
      for (int r = 0; r < 4; r++)
        qkv[(size_t)(rbase + r) * 2304 + col] = (bf16_t)((a[r] + bcol) * sc);
    }
  }
}

// ---------------- sparse windowed attention: one wave per (b, w, h), plain qkv layout ----------------
__global__ __launch_bounds__(64) void attn_kernel(const bf16_t* __restrict__ qkv,
                                                  bf16_t* __restrict__ ctx) {
  __shared__ float Ks[20][64];
  __shared__ float Vs[20][64];
  int id = blockIdx.x;               // ((b*128 + w)*12 + h)
  int h = id % 12;
  int bw = id / 12;
  int w = bw & 127, b = bw >> 7;
  int t = threadIdx.x;
  const int hc = h * 64;

  { // window-token K/V rows 0..15
    int j = t >> 2, dd = (t & 3) * 16;
    size_t row = (size_t)b * 2560 + w * 16 + j;
    const bf16_t* kp = qkv + row * 2304 + 768 + hc + dd;
    bf16x8 k0 = *(const bf16x8*)kp;
    bf16x8 k1 = *(const bf16x8*)(kp + 8);
    bf16x8 u0 = *(const bf16x8*)(kp + 768);
    bf16x8 u1 = *(const bf16x8*)(kp + 776);
    #pragma unroll
    for (int i = 0; i < 8; i++) {
      Ks[j][dd + i] = (float)k0[i]; Ks[j][dd + 8 + i] = (float)k1[i];
      Vs[j][dd + i] = (float)u0[i]; Vs[j][dd + 8 + i] = (float)u1[i];
    }
  }
  if (t < 16) { // carrier K/V rows 16..19
    int j = 16 + (t >> 2), dd = (t & 3) * 16;
    size_t row = (size_t)b * 2560 + 2048 + w * 4 + (t >> 2);
    const bf16_t* kp = qkv + row * 2304 + 768 + hc + dd;
    bf16x8 k0 = *(const bf16x8*)kp;
    bf16x8 k1 = *(const bf16x8*)(kp + 8);
    bf16x8 u0 = *(const bf16x8*)(kp + 768);
    bf16x8 u1 = *(const bf16x8*)(kp + 776);
    #pragma unroll
    for (int i = 0; i < 8; i++) {
      Ks[j][dd + i] = (float)k0[i]; Ks[j][dd + 8 + i] = (float)k1[i];
      Vs[j][dd + i] = (float)u0[i]; Vs[j][dd + 8 + i] = (float)u1[i];
    }
  }
  __syncthreads();

  int qi = t >> 2, c4 = t & 3, d0 = c4 * 16;
  float qreg[16];
  {
    const bf16_t* qp = qkv + ((size_t)b * 2560 + w * 16 + qi) * 2304 + hc + d0;
    bf16x8 q0 = *(const bf16x8*)qp;
    bf16x8 q1 = *(const bf16x8*)(qp + 8);
    #pragma unroll
    for (int i = 0; i < 8; i++) { qreg[i] = (float)q0[i]; qreg[8 + i] = (float)q1[i]; }
  }

  float pl[5];
  #pragma unroll
  for (int j = 0; j < 20; j++) {
    float s = 0.f;
    #pragma unroll
    for (int i = 0; i < 16; i++) s += qreg[i] * Ks[j][d0 + i];
    s += __shfl_xor(s, 1);
    s += __shfl_xor(s, 2);
    if ((j & 3) == c4) pl[j >> 2] = s;
  }
  float m = fmaxf(fmaxf(fmaxf(pl[0], pl[1]), fmaxf(pl[2], pl[3])), pl[4]);
  m = fmaxf(m, __shfl_xor(m, 1));
  m = fmaxf(m, __shfl_xor(m, 2));
  float sum = 0.f;
  #pragma unroll
  for (int i = 0; i < 5; i++) { pl[i] = __expf(pl[i] - m); sum += pl[i]; }
  sum += __shfl_xor(sum, 1);
  sum += __shfl_xor(sum, 2);
  float inv = 1.f / sum;

  float acc[16] = {};
  #pragma unroll
  for (int j = 0; j < 20; j++) {
    float pj = __shfl(pl[j >> 2], (qi << 2) | (j & 3));
    #pragma unroll
    for (int i = 0; i < 16; i++) acc[i] += pj * Vs[j][d0 + i];
  }

  bf16_t* cp = ctx + ((size_t)(b * 2048 + w * 16 + qi)) * 768 + hc + d0;
  #pragma unroll
  for (int i = 0; i < 16; i++) cp[i] = (bf16_t)(acc[i] * inv);
}

// ---------------- launch ----------------
extern "C" void kernel_launch(void* const* d_in, const int* in_sizes, int n_in,
                              void* d_out, int out_size, void* d_ws, size_t ws_size,
                              hipStream_t stream) {
  (void)in_sizes; (void)n_in; (void)out_size; (void)ws_size;
  const float* x      = (const float*)d_in[0];
  const float* W_qkv  = (const float*)d_in[1];
  const float* b_qkv  = (const float*)d_in[2];
  const float* W_car  = (const float*)d_in[3];
  const float* b_car  = (const float*)d_in[4];
  const float* W_proj = (const float*)d_in[5];
  const float* b_proj = (const float*)d_in[6];
  const float* gamma  = (const float*)d_in[7];
  const float* beta   = (const float*)d_in[8];
  float* out = (float*)d_out;

  char* ws = (char*)d_ws;
  bf16_t* wt_qkv  = (bf16_t*)(ws + OFF_WT_QKV);
  bf16_t* wt_car  = (bf16_t*)(ws + OFF_WT_CAR);
  bf16_t* wt_proj = (bf16_t*)(ws + OFF_WT_PROJ);
  bf16_t* wmean   = (bf16_t*)(ws + OFF_WMEAN);
  float*  carP    = (float*) (ws + OFF_CARP);
  bf16_t* ln      = (bf16_t*)(ws + OFF_LN);
  bf16_t* qkv     = (bf16_t*)(ws + OFF_QKV);
  bf16_t* ctx     = (bf16_t*)(ws + OFF_CTX);

  // 1. fused prep: weight transposes + window means
  prep_kernel<<<3136, 256, 0, stream>>>(W_qkv, W_car, W_proj, x,
                                        wt_qkv, wt_car, wt_proj, wmean);
  // 2. carrier GEMM, split-K=4 -> partials [4][256][768]
  gemm64_kernel<<<4 * 6 * 4, 256, 0, stream>>>(wmean, wt_car, nullptr, carP,
                                               4, 6, 192, 0);
  // 3. LayerNorm(combined) -> bf16  (sums car partials + b_car inline)
  ln_kernel<<<5120, 256, 0, stream>>>(x, carP, b_car, gamma, beta, ln);
  // 4. QKV projection -> plain [5120][2304] bf16
  //    DIAGNOSTIC: launched twice (idempotent) -> t_qkv = dur_us(this round) - 83 - gap
  gemm_qkv<<<40 * 18, 256, 0, stream>>>(ln, wt_qkv, b_qkv, qkv, 40);
  gemm_qkv<<<40 * 18, 256, 0, stream>>>(ln, wt_qkv, b_qkv, qkv, 40);
  // 5. sparse windowed attention -> ctx bf16
  attn_kernel<<<2 * 128 * 12, 64, 0, stream>>>(qkv, ctx);
  // 6. output projection -> d_out fp32
  gemm64_kernel<<<64 * 6, 256, 0, stream>>>(ctx, wt_proj, b_proj, out,
                                            64, 6, 768, 2);
}

// Round 6
// 83.238 us; speedup vs baseline: 1.3166x; 1.3166x over previous
//
#include <hip/hip_runtime.h>

typedef __bf16 bf16_t;
typedef __bf16 bf16x8 __attribute__((ext_vector_type(8)));
typedef float f32x4 __attribute__((ext_vector_type(4)));

#define GK 768   // inner K dim for every GEMM in this problem

// ---------------- workspace layout (bytes) ----------------
static constexpr size_t OFF_WT_QKV = 0;                                  // [2304][768] bf16
static constexpr size_t OFF_WT_CAR  = OFF_WT_QKV + (size_t)2304*768*2;   // [768][768] bf16
static constexpr size_t OFF_WT_PROJ = OFF_WT_CAR + (size_t)768*768*2;    // [768][768] bf16
static constexpr size_t OFF_WMEAN   = OFF_WT_PROJ + (size_t)768*768*2;   // [256][768] bf16
static constexpr size_t OFF_CARP    = OFF_WMEAN + (size_t)256*768*2;     // [4][256][768] f32 split-K partials
static constexpr size_t OFF_LN      = OFF_CARP + (size_t)4*256*768*4;    // [5120][768] bf16
static constexpr size_t OFF_QKV     = OFF_LN + (size_t)5120*768*2;       // [5120][2304] bf16 (q|k|v)
static constexpr size_t OFF_CTX     = OFF_QKV + (size_t)5120*2304*2;     // [2][2048][768] bf16

// ---------------- async global->LDS (16B per lane) ----------------
__device__ __forceinline__ void gload16(const bf16_t* g, bf16_t* lds_wave_base) {
  __builtin_amdgcn_global_load_lds(
      (const __attribute__((address_space(1))) unsigned int*)g,
      (__attribute__((address_space(3))) unsigned int*)lds_wave_base,
      16, 0, 0);
}

// ---------------- fused prep: 3 weight transposes (fp32->bf16, W[K][N]->Wt[N][K]) + window means ----------------
__global__ __launch_bounds__(256) void prep_kernel(const float* __restrict__ W_qkv,
                                                   const float* __restrict__ W_car,
                                                   const float* __restrict__ W_proj,
                                                   const float* __restrict__ x,
                                                   bf16_t* __restrict__ wt_qkv,
                                                   bf16_t* __restrict__ wt_car,
                                                   bf16_t* __restrict__ wt_proj,
                                                   bf16_t* __restrict__ wm) {
  int bid = blockIdx.x;
  if (bid < 2880) {
    __shared__ float tile[32][33];
    const float* W; bf16_t* Wt; int Ndim, kb, nb;
    if (bid < 1728) {
      W = W_qkv; Wt = wt_qkv; Ndim = 2304; kb = (bid % 24) * 32; nb = (bid / 24) * 32;
    } else if (bid < 2304) {
      int q = bid - 1728; W = W_car; Wt = wt_car; Ndim = 768; kb = (q % 24) * 32; nb = (q / 24) * 32;
    } else {
      int q = bid - 2304; W = W_proj; Wt = wt_proj; Ndim = 768; kb = (q % 24) * 32; nb = (q / 24) * 32;
    }
    int tx = threadIdx.x & 31, ty = threadIdx.x >> 5;   // ty in 0..7
    #pragma unroll
    for (int i = 0; i < 32; i += 8)
      tile[ty + i][tx] = W[(size_t)(kb + ty + i) * Ndim + nb + tx];
    __syncthreads();
    #pragma unroll
    for (int i = 0; i < 32; i += 8)
      Wt[(size_t)(nb + ty + i) * GK + kb + tx] = (bf16_t)tile[tx][ty + i];
  } else {
    int w = bid - 2880;            // 0..255  (b*128 + window)
    int b = w >> 7, ww = w & 127;
    const float* base = x + ((size_t)b * 2048 + (size_t)ww * 16) * 768;
    for (int d = threadIdx.x; d < 768; d += 256) {
      float s = 0.f;
      #pragma unroll
      for (int i = 0; i < 16; i++) s += base[(size_t)i * 768 + d];
      wm[(size_t)w * 768 + d] = (bf16_t)(s * (1.f / 16.f));
    }
  }
}

// ---------------- 64x128-tile bf16 MFMA GEMM with optional split-K ----------------
__global__ __launch_bounds__(256) void gemm64_kernel(const bf16_t* __restrict__ A,
                                                     const bf16_t* __restrict__ Bt,
                                                     const float* __restrict__ bias,
                                                     float* __restrict__ outF,
                                                     int mB, int nB, int kspan, int mode) {
  __shared__ __align__(16) bf16_t As[64 * 32];
  __shared__ __align__(16) bf16_t Bs[128 * 32];
  int bid = blockIdx.x;
  int bm = bid % mB;
  int rest = bid / mB;
  int bn = rest % nB;
  int kz = rest / nB;
  int t = threadIdx.x, wid = t >> 6, lane = t & 63;
  int wm = wid >> 1, wn = wid & 1;
  int sr = t >> 2, sk = (t & 3) * 8;
  const bf16_t* gA = A + (size_t)(bm * 64 + sr) * GK + sk;
  const bf16_t* gB = Bt + (size_t)(bn * 128 + sr) * GK + sk;
  bf16_t* lA  = As + wid * 512;
  bf16_t* lB0 = Bs + wid * 512;
  bf16_t* lB1 = Bs + 2048 + wid * 512;
  int fr = lane & 15, fk = (lane >> 4) * 8;

  f32x4 acc[2][4] = {};
  int k0 = kz * kspan, kend = k0 + kspan;
  for (; k0 < kend; k0 += 32) {
    gload16(gA + k0,           lA);
    gload16(gB + k0,           lB0);
    gload16(gB + k0 + 64 * GK, lB1);
    __syncthreads();
    bf16x8 af[2], bfr[4];
    #pragma unroll
    for (int i = 0; i < 2; i++)
      af[i] = *(const bf16x8*)(As + (wm * 32 + i * 16 + fr) * 32 + fk);
    #pragma unroll
    for (int j = 0; j < 4; j++)
      bfr[j] = *(const bf16x8*)(Bs + (wn * 64 + j * 16 + fr) * 32 + fk);
    #pragma unroll
    for (int i = 0; i < 2; i++)
      #pragma unroll
      for (int j = 0; j < 4; j++)
        acc[i][j] = __builtin_amdgcn_mfma_f32_16x16x32_bf16(af[i], bfr[j], acc[i][j], 0, 0, 0);
    __syncthreads();
  }

  #pragma unroll
  for (int i = 0; i < 2; i++) {
    int rbase = bm * 64 + wm * 32 + i * 16 + ((lane >> 4) << 2);
    #pragma unroll
    for (int j = 0; j < 4; j++) {
      int col = bn * 128 + wn * 64 + j * 16 + (lane & 15);
      f32x4 a = acc[i][j];
      float bcol = (mode == 2) ? bias[col] : 0.f;
      #pragma unroll
      for (int r = 0; r < 4; r++) {
        int row = rbase + r;
        if (mode == 0)
          outF[(size_t)kz * 196608 + (size_t)row * 768 + col] = a[r];
        else
          outF[(size_t)row * 768 + col] = a[r] + bcol;
      }
    }
  }
}

// ---------------- fused LayerNorm over "combined" rows -> bf16 ----------------
__global__ __launch_bounds__(256) void ln_kernel(const float* __restrict__ x,
                                                 const float* __restrict__ carP,
                                                 const float* __restrict__ b_car,
                                                 const float* __restrict__ gamma,
                                                 const float* __restrict__ beta,
                                                 bf16_t* __restrict__ out) {
  __shared__ float red[8];
  int row = blockIdx.x;                 // 0 .. 5119
  int b = row / 2560, n = row - b * 2560;
  int t = threadIdx.x;
  float v0, v1, v2;
  if (n < 2048) {
    const float* src = x + ((size_t)b * 2048 + n) * 768;
    v0 = src[t]; v1 = src[t + 256]; v2 = src[t + 512];
  } else {
    size_t ci = (size_t)(b * 128 + ((n - 2048) >> 2)) * 768;
    const float* p0 = carP + ci;
    const float* p1 = carP + ci + 196608;
    const float* p2 = carP + ci + 2 * 196608;
    const float* p3 = carP + ci + 3 * 196608;
    v0 = p0[t]       + p1[t]       + p2[t]       + p3[t]       + b_car[t];
    v1 = p0[t + 256] + p1[t + 256] + p2[t + 256] + p3[t + 256] + b_car[t + 256];
    v2 = p0[t + 512] + p1[t + 512] + p2[t + 512] + p3[t + 512] + b_car[t + 512];
  }
  float s = v0 + v1 + v2;
  float q = v0 * v0 + v1 * v1 + v2 * v2;
  #pragma unroll
  for (int o = 32; o > 0; o >>= 1) { s += __shfl_down(s, o); q += __shfl_down(q, o); }
  int wv = t >> 6;
  if ((t & 63) == 0) { red[wv] = s; red[4 + wv] = q; }
  __syncthreads();
  s = red[0] + red[1] + red[2] + red[3];
  q = red[4] + red[5] + red[6] + red[7];
  float mean = s * (1.f / 768.f);
  float var  = q * (1.f / 768.f) - mean * mean;
  float rstd = rsqrtf(var + 1e-5f);
  bf16_t* o0 = out + (size_t)row * 768;
  o0[t]       = (bf16_t)((v0 - mean) * rstd * gamma[t]       + beta[t]);
  o0[t + 256] = (bf16_t)((v1 - mean) * rstd * gamma[t + 256] + beta[t + 256]);
  o0[t + 512] = (bf16_t)((v2 - mean) * rstd * gamma[t + 512] + beta[t + 512]);
}

// ---------------- QKV GEMM: 256x256 tile, BK=64, 4-phase/tile pipelined schedule ----------------
// 512 thr = 8 waves (2M x 4N); per-wave out 128x64 (acc[8][4]); 12 K-tiles (GK/64).
// LDS: 2 slots x {A,B} x [2 kk-subtiles][256 rows][32 k] bf16 = 128KB.
// Each kk-subtile is contiguous (16KB) and independently swizzled: chunk ^= (r>>1)&3
// (8 distinct banks per 8 rows -> 2-way, free). global_load_lds writes linearly;
// the global SOURCE address carries the inverse swizzle (both-sides rule, m173/#21).
// Stages during tile T target slot s^1 ONLY (tile T+1): slot s^1's previous reads
// (tile T-1) completed before the boundary barrier -> WAR-free by construction.
// Counted waits: vmcnt(2) at q0-end (q1 reads B-kk1), vmcnt(4) at q3-end (next kk0);
// each wait precedes a barrier that precedes the dependent reads (cross-wave rule).
__global__ __launch_bounds__(512, 2) void gemm256_qkv(const bf16_t* __restrict__ A,
                                                      const bf16_t* __restrict__ Bt,
                                                      const float* __restrict__ bias,
                                                      bf16_t* __restrict__ qkv) {
  __shared__ __align__(16) bf16_t smem[2][2][16384];   // [slot][A=0/B=1][kk*8192 + r*32 + swz]

  // bijective XCD swizzle (m204): nwg=180, xcd 0..3 get 23 blocks, 4..7 get 22
  int xcd = blockIdx.x & 7, idx = blockIdx.x >> 3;
  int wgid = (xcd < 4 ? xcd * 23 : 92 + (xcd - 4) * 22) + idx;
  int bm = wgid / 9, bn = wgid % 9;

  int t = threadIdx.x;
  int w = t >> 6, lane = t & 63;
  int wm = w >> 2, wn = w & 3;          // wm: 128-row band, wn: 64-col band
  int fr = lane & 15, s16 = lane >> 4;

  const bf16_t* Ab = A  + (size_t)bm * 256 * GK;
  const bf16_t* Bb = Bt + (size_t)bn * 256 * GK;

  // staging: thread t covers LDS bytes l*8192 + t*16 of a kk-subtile
  //  -> row r = l*128 + (t>>2), stored chunk pos p = t&3, content chunk c = p ^ ((r>>1)&3)
  const int srow  = t >> 2;                              // 0..127 (line 0)
  const int skoff = (((t & 3) ^ ((t >> 3) & 3)) << 3);   // inverse-swizzled k-elem offset
  const int wbase = w * 512;                             // wave-uniform dest (HW adds lane*16B)

  auto stageH = [&](const bf16_t* src, int mat, int kk, int T, int s) {
    const bf16_t* g = src + (size_t)srow * GK + T * 64 + kk * 32 + skoff;
    gload16(g,            &smem[s][mat][kk * 8192 + wbase]);
    gload16(g + 128 * GK, &smem[s][mat][kk * 8192 + 4096 + wbase]);
  };
  // fragment read: row r, content chunk s16 -> position s16 ^ ((r>>1)&3)
  auto rdA = [&](int s, int m, int kk) -> bf16x8 {
    int r = wm * 128 + m * 16 + fr;
    return *(const bf16x8*)(&smem[s][0][kk * 8192 + r * 32 + ((s16 ^ ((r >> 1) & 3)) << 3)]);
  };
  auto rdB = [&](int s, int n, int kk) -> bf16x8 {
    int r = wn * 64 + n * 16 + fr;
    return *(const bf16x8*)(&smem[s][1][kk * 8192 + r * 32 + ((s16 ^ ((r >> 1) & 3)) << 3)]);
  };

  f32x4 acc[8][4] = {};

  // prologue: tile 0 -> slot 0, issue order kk0(A,B) then kk1(A,B)
  stageH(Ab, 0, 0, 0, 0); stageH(Bb, 1, 0, 0, 0);
  stageH(Ab, 0, 1, 0, 0); stageH(Bb, 1, 1, 0, 0);
  asm volatile("s_waitcnt vmcnt(4)" ::: "memory");   // kk0 landed; kk1 (4 lines) in flight
  __builtin_amdgcn_s_barrier();

  #pragma unroll 1
  for (int T = 0; T < 12; ++T) {                     // 12 = GK/64  (R5 bug: was 24)
    const int s = T & 1;
    const bool pf = (T < 11);
    bf16x8 bf0[4], bf1[4];
    { // ---- q0: stage A-kk0(T+1); read B-kk0 + A-kk0 m0-3; MFMA ----
      if (pf) stageH(Ab, 0, 0, T + 1, s ^ 1);
      bf16x8 a0[4];
      #pragma unroll
      for (int n = 0; n < 4; n++) bf0[n] = rdB(s, n, 0);
      #pragma unroll
      for (int m = 0; m < 4; m++) a0[m] = rdA(s, m, 0);
      __builtin_amdgcn_s_barrier();
      __builtin_amdgcn_s_setprio(1);
      #pragma unroll
      for (int m = 0; m < 4; m++)
        #pragma unroll
        for (int n = 0; n < 4; n++)
          acc[m][n] = __builtin_amdgcn_mfma_f32_16x16x32_bf16(a0[m], bf0[n], acc[m][n], 0, 0, 0);
      __builtin_amdgcn_s_setprio(0);
      if (pf) asm volatile("s_waitcnt vmcnt(2)" ::: "memory");   // this tile's kk1 landed
      else    asm volatile("s_waitcnt vmcnt(0)" ::: "memory");
      __builtin_amdgcn_s_barrier();
    }
    { // ---- q1: stage B-kk0(T+1); read B-kk1 + A-kk0 m4-7; MFMA ----
      if (pf) stageH(Bb, 1, 0, T + 1, s ^ 1);
      bf16x8 a1[4];
      #pragma unroll
      for (int n = 0; n < 4; n++) bf1[n] = rdB(s, n, 1);
      #pragma unroll
      for (int m = 0; m < 4; m++) a1[m] = rdA(s, 4 + m, 0);
      __builtin_amdgcn_s_barrier();
      __builtin_amdgcn_s_setprio(1);
      #pragma unroll
      for (int m = 0; m < 4; m++)
        #pragma unroll
        for (int n = 0; n < 4; n++)
          acc[4 + m][n] = __builtin_amdgcn_mfma_f32_16x16x32_bf16(a1[m], bf0[n], acc[4 + m][n], 0, 0, 0);
      __builtin_amdgcn_s_setprio(0);
      __builtin_amdgcn_s_barrier();
    }
    { // ---- q2: stage A-kk1(T+1); read A-kk1 m0-3; MFMA ----
      if (pf) stageH(Ab, 0, 1, T + 1, s ^ 1);
      bf16x8 a2[4];
      #pragma unroll
      for (int m = 0; m < 4; m++) a2[m] = rdA(s, m, 1);
      __builtin_amdgcn_s_barrier();
      __builtin_amdgcn_s_setprio(1);
      #pragma unroll
      for (int m = 0; m < 4; m++)
        #pragma unroll
        for (int n = 0; n < 4; n++)
          acc[m][n] = __builtin_amdgcn_mfma_f32_16x16x32_bf16(a2[m], bf1[n], acc[m][n], 0, 0, 0);
      __builtin_amdgcn_s_setprio(0);
      __builtin_amdgcn_s_barrier();
    }
    { // ---- q3: stage B-kk1(T+1); read A-kk1 m4-7; MFMA; boundary wait ----
      if (pf) stageH(Bb, 1, 1, T + 1, s ^ 1);
      bf16x8 a3[4];
      #pragma unroll
      for (int m = 0; m < 4; m++) a3[m] = rdA(s, 4 + m, 1);
      __builtin_amdgcn_s_barrier();
      __builtin_amdgcn_s_setprio(1);
      #pragma unroll
      for (int m = 0; m < 4; m++)
        #pragma unroll
        for (int n = 0; n < 4; n++)
          acc[4 + m][n] = __builtin_amdgcn_mfma_f32_16x16x32_bf16(a3[m], bf1[n], acc[4 + m][n], 0, 0, 0);
      __builtin_amdgcn_s_setprio(0);
      if (pf) asm volatile("s_waitcnt vmcnt(4)" ::: "memory");   // next tile's kk0 landed
      __builtin_amdgcn_s_barrier();
    }
  }

  // epilogue: D layout col = lane&15, row = (lane>>4)*4 + reg; plain row-major store
  #pragma unroll
  for (int m = 0; m < 8; m++) {
    int rbase = bm * 256 + wm * 128 + m * 16 + (s16 << 2);
    #pragma unroll
    for (int n = 0; n < 4; n++) {
      int col = bn * 256 + wn * 64 + n * 16 + fr;
      float bcol = bias[col];
      float sc = (col < 768) ? 0.125f : 1.f;   // fold SCALE into q section
      f32x4 a = acc[m][n];
      #pragma unroll
      for (int r2 = 0; r2 < 4; r2++)
        qkv[(size_t)(rbase + r2) * 2304 + col] = (bf16_t)((a[r2] + bcol) * sc);
    }
  }
}

// ---------------- sparse windowed attention: one wave per (b, w, h), plain qkv layout ----------------
__global__ __launch_bounds__(64) void attn_kernel(const bf16_t* __restrict__ qkv,
                                                  bf16_t* __restrict__ ctx) {
  __shared__ float Ks[20][64];
  __shared__ float Vs[20][64];
  int id = blockIdx.x;               // ((b*128 + w)*12 + h)
  int h = id % 12;
  int bw = id / 12;
  int w = bw & 127, b = bw >> 7;
  int t = threadIdx.x;
  const int hc = h * 64;

  { // window-token K/V rows 0..15
    int j = t >> 2, dd = (t & 3) * 16;
    size_t row = (size_t)b * 2560 + w * 16 + j;
    const bf16_t* kp = qkv + row * 2304 + 768 + hc + dd;
    bf16x8 k0 = *(const bf16x8*)kp;
    bf16x8 k1 = *(const bf16x8*)(kp + 8);
    bf16x8 u0 = *(const bf16x8*)(kp + 768);
    bf16x8 u1 = *(const bf16x8*)(kp + 776);
    #pragma unroll
    for (int i = 0; i < 8; i++) {
      Ks[j][dd + i] = (float)k0[i]; Ks[j][dd + 8 + i] = (float)k1[i];
      Vs[j][dd + i] = (float)u0[i]; Vs[j][dd + 8 + i] = (float)u1[i];
    }
  }
  if (t < 16) { // carrier K/V rows 16..19
    int j = 16 + (t >> 2), dd = (t & 3) * 16;
    size_t row = (size_t)b * 2560 + 2048 + w * 4 + (t >> 2);
    const bf16_t* kp = qkv + row * 2304 + 768 + hc + dd;
    bf16x8 k0 = *(const bf16x8*)kp;
    bf16x8 k1 = *(const bf16x8*)(kp + 8);
    bf16x8 u0 = *(const bf16x8*)(kp + 768);
    bf16x8 u1 = *(const bf16x8*)(kp + 776);
    #pragma unroll
    for (int i = 0; i < 8; i++) {
      Ks[j][dd + i] = (float)k0[i]; Ks[j][dd + 8 + i] = (float)k1[i];
      Vs[j][dd + i] = (float)u0[i]; Vs[j][dd + 8 + i] = (float)u1[i];
    }
  }
  __syncthreads();

  int qi = t >> 2, c4 = t & 3, d0 = c4 * 16;
  float qreg[16];
  {
    const bf16_t* qp = qkv + ((size_t)b * 2560 + w * 16 + qi) * 2304 + hc + d0;
    bf16x8 q0 = *(const bf16x8*)qp;
    bf16x8 q1 = *(const bf16x8*)(qp + 8);
    #pragma unroll
    for (int i = 0; i < 8; i++) { qreg[i] = (float)q0[i]; qreg[8 + i] = (float)q1[i]; }
  }

  float pl[5];
  #pragma unroll
  for (int j = 0; j < 20; j++) {
    float s = 0.f;
    #pragma unroll
    for (int i = 0; i < 16; i++) s += qreg[i] * Ks[j][d0 + i];
    s += __shfl_xor(s, 1);
    s += __shfl_xor(s, 2);
    if ((j & 3) == c4) pl[j >> 2] = s;
  }
  float m = fmaxf(fmaxf(fmaxf(pl[0], pl[1]), fmaxf(pl[2], pl[3])), pl[4]);
  m = fmaxf(m, __shfl_xor(m, 1));
  m = fmaxf(m, __shfl_xor(m, 2));
  float sum = 0.f;
  #pragma unroll
  for (int i = 0; i < 5; i++) { pl[i] = __expf(pl[i] - m); sum += pl[i]; }
  sum += __shfl_xor(sum, 1);
  sum += __shfl_xor(sum, 2);
  float inv = 1.f / sum;

  float acc[16] = {};
  #pragma unroll
  for (int j = 0; j < 20; j++) {
    float pj = __shfl(pl[j >> 2], (qi << 2) | (j & 3));
    #pragma unroll
    for (int i = 0; i < 16; i++) acc[i] += pj * Vs[j][d0 + i];
  }

  bf16_t* cp = ctx + ((size_t)(b * 2048 + w * 16 + qi)) * 768 + hc + d0;
  #pragma unroll
  for (int i = 0; i < 16; i++) cp[i] = (bf16_t)(acc[i] * inv);
}

// ---------------- launch ----------------
extern "C" void kernel_launch(void* const* d_in, const int* in_sizes, int n_in,
                              void* d_out, int out_size, void* d_ws, size_t ws_size,
                              hipStream_t stream) {
  (void)in_sizes; (void)n_in; (void)out_size; (void)ws_size;
  const float* x      = (const float*)d_in[0];
  const float* W_qkv  = (const float*)d_in[1];
  const float* b_qkv  = (const float*)d_in[2];
  const float* W_car  = (const float*)d_in[3];
  const float* b_car  = (const float*)d_in[4];
  const float* W_proj = (const float*)d_in[5];
  const float* b_proj = (const float*)d_in[6];
  const float* gamma  = (const float*)d_in[7];
  const float* beta   = (const float*)d_in[8];
  float* out = (float*)d_out;

  char* ws = (char*)d_ws;
  bf16_t* wt_qkv  = (bf16_t*)(ws + OFF_WT_QKV);
  bf16_t* wt_car  = (bf16_t*)(ws + OFF_WT_CAR);
  bf16_t* wt_proj = (bf16_t*)(ws + OFF_WT_PROJ);
  bf16_t* wmean   = (bf16_t*)(ws + OFF_WMEAN);
  float*  carP    = (float*) (ws + OFF_CARP);
  bf16_t* ln      = (bf16_t*)(ws + OFF_LN);
  bf16_t* qkv     = (bf16_t*)(ws + OFF_QKV);
  bf16_t* ctx     = (bf16_t*)(ws + OFF_CTX);

  // 1. fused prep: weight transposes + window means
  prep_kernel<<<3136, 256, 0, stream>>>(W_qkv, W_car, W_proj, x,
                                        wt_qkv, wt_car, wt_proj, wmean);
  // 2. carrier GEMM, split-K=4 -> partials [4][256][768]
  gemm64_kernel<<<4 * 6 * 4, 256, 0, stream>>>(wmean, wt_car, nullptr, carP,
                                               4, 6, 192, 0);
  // 3. LayerNorm(combined) -> bf16  (sums car partials + b_car inline)
  ln_kernel<<<5120, 256, 0, stream>>>(x, carP, b_car, gamma, beta, ln);
  // 4. QKV projection: 256^2 pipelined GEMM -> plain [5120][2304] bf16
  gemm256_qkv<<<180, 512, 0, stream>>>(ln, wt_qkv, b_qkv, qkv);
  // 5. sparse windowed attention -> ctx bf16
  attn_kernel<<<2 * 128 * 12, 64, 0, stream>>>(qkv, ctx);
  // 6. output projection -> d_out fp32
  gemm64_kernel<<<64 * 6, 256, 0, stream>>>(ctx, wt_proj, b_proj, out,
                                            64, 6, 768, 2);
}

// Round 7
// 81.584 us; speedup vs baseline: 1.3433x; 1.0203x over previous
//
#include <hip/hip_runtime.h>

typedef __bf16 bf16_t;
typedef __bf16 bf16x8 __attribute__((ext_vector_type(8)));
typedef float f32x4 __attribute__((ext_vector_type(4)));

#define GK 768   // inner K dim for every GEMM in this problem

// ---------------- workspace layout (bytes) ----------------
static constexpr size_t OFF_WT_QKV = 0;                                  // [2304][768] bf16
static constexpr size_t OFF_WT_CAR  = OFF_WT_QKV + (size_t)2304*768*2;   // [768][768] bf16
static constexpr size_t OFF_WT_PROJ = OFF_WT_CAR + (size_t)768*768*2;    // [768][768] bf16
static constexpr size_t OFF_WMEAN   = OFF_WT_PROJ + (size_t)768*768*2;   // [256][768] bf16
static constexpr size_t OFF_CARP    = OFF_WMEAN + (size_t)256*768*2;     // [4][256][768] f32 split-K partials
static constexpr size_t OFF_LN      = OFF_CARP + (size_t)4*256*768*4;    // [5120][768] bf16
static constexpr size_t OFF_QKV     = OFF_LN + (size_t)5120*768*2;       // [5120][2304] bf16 (q|k|v)
static constexpr size_t OFF_CTX     = OFF_QKV + (size_t)5120*2304*2;     // [2][2048][768] bf16

// ---------------- async global->LDS (16B per lane) ----------------
__device__ __forceinline__ void gload16(const bf16_t* g, bf16_t* lds_wave_base) {
  __builtin_amdgcn_global_load_lds(
      (const __attribute__((address_space(1))) unsigned int*)g,
      (__attribute__((address_space(3))) unsigned int*)lds_wave_base,
      16, 0, 0);
}

// ---------------- fused prep: 3 weight transposes (fp32->bf16, W[K][N]->Wt[N][K]) + window means ----------------
__global__ __launch_bounds__(256) void prep_kernel(const float* __restrict__ W_qkv,
                                                   const float* __restrict__ W_car,
                                                   const float* __restrict__ W_proj,
                                                   const float* __restrict__ x,
                                                   bf16_t* __restrict__ wt_qkv,
                                                   bf16_t* __restrict__ wt_car,
                                                   bf16_t* __restrict__ wt_proj,
                                                   bf16_t* __restrict__ wm) {
  int bid = blockIdx.x;
  if (bid < 2880) {
    __shared__ float tile[32][33];
    const float* W; bf16_t* Wt; int Ndim, kb, nb;
    if (bid < 1728) {
      W = W_qkv; Wt = wt_qkv; Ndim = 2304; kb = (bid % 24) * 32; nb = (bid / 24) * 32;
    } else if (bid < 2304) {
      int q = bid - 1728; W = W_car; Wt = wt_car; Ndim = 768; kb = (q % 24) * 32; nb = (q / 24) * 32;
    } else {
      int q = bid - 2304; W = W_proj; Wt = wt_proj; Ndim = 768; kb = (q % 24) * 32; nb = (q / 24) * 32;
    }
    int tx = threadIdx.x & 31, ty = threadIdx.x >> 5;   // ty in 0..7
    #pragma unroll
    for (int i = 0; i < 32; i += 8)
      tile[ty + i][tx] = W[(size_t)(kb + ty + i) * Ndim + nb + tx];
    __syncthreads();
    #pragma unroll
    for (int i = 0; i < 32; i += 8)
      Wt[(size_t)(nb + ty + i) * GK + kb + tx] = (bf16_t)tile[tx][ty + i];
  } else {
    int w = bid - 2880;            // 0..255  (b*128 + window)
    int b = w >> 7, ww = w & 127;
    const float* base = x + ((size_t)b * 2048 + (size_t)ww * 16) * 768;
    for (int d = threadIdx.x; d < 768; d += 256) {
      float s = 0.f;
      #pragma unroll
      for (int i = 0; i < 16; i++) s += base[(size_t)i * 768 + d];
      wm[(size_t)w * 768 + d] = (bf16_t)(s * (1.f / 16.f));
    }
  }
}

// ---------------- 64x128-tile bf16 MFMA GEMM with optional split-K ----------------
__global__ __launch_bounds__(256) void gemm64_kernel(const bf16_t* __restrict__ A,
                                                     const bf16_t* __restrict__ Bt,
                                                     const float* __restrict__ bias,
                                                     float* __restrict__ outF,
                                                     int mB, int nB, int kspan, int mode) {
  __shared__ __align__(16) bf16_t As[64 * 32];
  __shared__ __align__(16) bf16_t Bs[128 * 32];
  int bid = blockIdx.x;
  int bm = bid % mB;
  int rest = bid / mB;
  int bn = rest % nB;
  int kz = rest / nB;
  int t = threadIdx.x, wid = t >> 6, lane = t & 63;
  int wm = wid >> 1, wn = wid & 1;
  int sr = t >> 2, sk = (t & 3) * 8;
  const bf16_t* gA = A + (size_t)(bm * 64 + sr) * GK + sk;
  const bf16_t* gB = Bt + (size_t)(bn * 128 + sr) * GK + sk;
  bf16_t* lA  = As + wid * 512;
  bf16_t* lB0 = Bs + wid * 512;
  bf16_t* lB1 = Bs + 2048 + wid * 512;
  int fr = lane & 15, fk = (lane >> 4) * 8;

  f32x4 acc[2][4] = {};
  int k0 = kz * kspan, kend = k0 + kspan;
  for (; k0 < kend; k0 += 32) {
    gload16(gA + k0,           lA);
    gload16(gB + k0,           lB0);
    gload16(gB + k0 + 64 * GK, lB1);
    __syncthreads();
    bf16x8 af[2], bfr[4];
    #pragma unroll
    for (int i = 0; i < 2; i++)
      af[i] = *(const bf16x8*)(As + (wm * 32 + i * 16 + fr) * 32 + fk);
    #pragma unroll
    for (int j = 0; j < 4; j++)
      bfr[j] = *(const bf16x8*)(Bs + (wn * 64 + j * 16 + fr) * 32 + fk);
    #pragma unroll
    for (int i = 0; i < 2; i++)
      #pragma unroll
      for (int j = 0; j < 4; j++)
        acc[i][j] = __builtin_amdgcn_mfma_f32_16x16x32_bf16(af[i], bfr[j], acc[i][j], 0, 0, 0);
    __syncthreads();
  }

  #pragma unroll
  for (int i = 0; i < 2; i++) {
    int rbase = bm * 64 + wm * 32 + i * 16 + ((lane >> 4) << 2);
    #pragma unroll
    for (int j = 0; j < 4; j++) {
      int col = bn * 128 + wn * 64 + j * 16 + (lane & 15);
      f32x4 a = acc[i][j];
      float bcol = (mode == 2) ? bias[col] : 0.f;
      #pragma unroll
      for (int r = 0; r < 4; r++) {
        int row = rbase + r;
        if (mode == 0)
          outF[(size_t)kz * 196608 + (size_t)row * 768 + col] = a[r];
        else
          outF[(size_t)row * 768 + col] = a[r] + bcol;
      }
    }
  }
}

// ---------------- fused LayerNorm over "combined" rows -> bf16 ----------------
__global__ __launch_bounds__(256) void ln_kernel(const float* __restrict__ x,
                                                 const float* __restrict__ carP,
                                                 const float* __restrict__ b_car,
                                                 const float* __restrict__ gamma,
                                                 const float* __restrict__ beta,
                                                 bf16_t* __restrict__ out) {
  __shared__ float red[8];
  int row = blockIdx.x;                 // 0 .. 5119
  int b = row / 2560, n = row - b * 2560;
  int t = threadIdx.x;
  float v0, v1, v2;
  if (n < 2048) {
    const float* src = x + ((size_t)b * 2048 + n) * 768;
    v0 = src[t]; v1 = src[t + 256]; v2 = src[t + 512];
  } else {
    size_t ci = (size_t)(b * 128 + ((n - 2048) >> 2)) * 768;
    const float* p0 = carP + ci;
    const float* p1 = carP + ci + 196608;
    const float* p2 = carP + ci + 2 * 196608;
    const float* p3 = carP + ci + 3 * 196608;
    v0 = p0[t]       + p1[t]       + p2[t]       + p3[t]       + b_car[t];
    v1 = p0[t + 256] + p1[t + 256] + p2[t + 256] + p3[t + 256] + b_car[t + 256];
    v2 = p0[t + 512] + p1[t + 512] + p2[t + 512] + p3[t + 512] + b_car[t + 512];
  }
  float s = v0 + v1 + v2;
  float q = v0 * v0 + v1 * v1 + v2 * v2;
  #pragma unroll
  for (int o = 32; o > 0; o >>= 1) { s += __shfl_down(s, o); q += __shfl_down(q, o); }
  int wv = t >> 6;
  if ((t & 63) == 0) { red[wv] = s; red[4 + wv] = q; }
  __syncthreads();
  s = red[0] + red[1] + red[2] + red[3];
  q = red[4] + red[5] + red[6] + red[7];
  float mean = s * (1.f / 768.f);
  float var  = q * (1.f / 768.f) - mean * mean;
  float rstd = rsqrtf(var + 1e-5f);
  bf16_t* o0 = out + (size_t)row * 768;
  o0[t]       = (bf16_t)((v0 - mean) * rstd * gamma[t]       + beta[t]);
  o0[t + 256] = (bf16_t)((v1 - mean) * rstd * gamma[t + 256] + beta[t + 256]);
  o0[t + 512] = (bf16_t)((v2 - mean) * rstd * gamma[t + 512] + beta[t + 512]);
}

// ---------------- QKV GEMM: 256x256 tile, BK=32, 3-slot ring, TRUE counted vmcnt ----------------
// 512 thr = 8 waves (2M x 4N); per-wave out 128x64 (acc[8][4]); 24 K-tiles (GK/32).
// LDS: 3 slots x {A,B} x [256 rows][32 k] bf16 = 96KB.  Swizzle: chunk ^= (r>>1)&3
// (both-sides rule: inverse applied on the global_load_lds SOURCE address).
// Ring discipline: tile T reads slot T%3; during T we stage tile T+2 into slot
// (T+2)%3, whose reads finished at tile T-1 (a barrier-boundary earlier) -> WAR-free.
// ONE wait per tile, vmcnt(4): each wave's 4 loads for T+2 stay in flight; the
// oldest (T+1's, issued during T-1) are certified landed. Never drains until T=22.
// Per-wave vmcnt THEN barrier -> cross-wave visibility correct.
__global__ __launch_bounds__(512, 1) void gemm256_qkv(const bf16_t* __restrict__ A,
                                                      const bf16_t* __restrict__ Bt,
                                                      const float* __restrict__ bias,
                                                      bf16_t* __restrict__ qkv) {
  __shared__ __align__(16) bf16_t smem[3][2][8192];   // [slot][A=0/B=1][r*32 + swz]

  // bijective XCD swizzle (m204): nwg=180, xcd 0..3 get 23 blocks, 4..7 get 22
  int xcd = blockIdx.x & 7, idx = blockIdx.x >> 3;
  int wgid = (xcd < 4 ? xcd * 23 : 92 + (xcd - 4) * 22) + idx;
  int bm = wgid / 9, bn = wgid % 9;

  int t = threadIdx.x;
  int w = t >> 6, lane = t & 63;
  int wm = w >> 2, wn = w & 3;          // wm: 128-row band, wn: 64-col band
  int fr = lane & 15, s16 = lane >> 4;

  const bf16_t* Ab = A  + (size_t)bm * 256 * GK;
  const bf16_t* Bb = Bt + (size_t)bn * 256 * GK;

  // staging: thread t covers 16B lines at bytes t*16 (row t>>2) and 8192+t*16 (row 128+(t>>2))
  // stored chunk pos p = t&3, content chunk c = p ^ ((r>>1)&3); (r>>1)&3 identical for both lines.
  const int srow  = t >> 2;                              // 0..127
  const int skoff = (((t & 3) ^ ((t >> 3) & 3)) << 3);   // inverse-swizzled k-elem offset
  const int wbase = w * 512;                             // wave-uniform dest (HW adds lane*16B)

  auto stageT = [&](const bf16_t* src, int mat, int T, int s) {
    const bf16_t* g = src + (size_t)srow * GK + T * 32 + skoff;
    gload16(g,            &smem[s][mat][wbase]);
    gload16(g + 128 * GK, &smem[s][mat][4096 + wbase]);
  };
  // fragment read: row r, content chunk s16 -> stored position s16 ^ ((r>>1)&3)
  auto rdA = [&](int s, int m) -> bf16x8 {
    int r = wm * 128 + m * 16 + fr;
    return *(const bf16x8*)(&smem[s][0][r * 32 + ((s16 ^ ((r >> 1) & 3)) << 3)]);
  };
  auto rdB = [&](int s, int n) -> bf16x8 {
    int r = wn * 64 + n * 16 + fr;
    return *(const bf16x8*)(&smem[s][1][r * 32 + ((s16 ^ ((r >> 1) & 3)) << 3)]);
  };

  f32x4 acc[8][4] = {};

  // prologue: tile 0 -> slot 0, tile 1 -> slot 1 (each wave: 8 loads)
  stageT(Ab, 0, 0, 0); stageT(Bb, 1, 0, 0);
  stageT(Ab, 0, 1, 1); stageT(Bb, 1, 1, 1);
  asm volatile("s_waitcnt vmcnt(4)" ::: "memory");   // tile 0 landed; tile 1's 4 in flight
  __builtin_amdgcn_s_barrier();

  int s = 0, s2 = 2;
  #pragma unroll 1
  for (int T = 0; T < 24; ++T) {
    const bool pf = (T <= 21);
    bf16x8 bfr[4], a0[4], a1[4];
    { // ---- q0: read B n0-3 + A m0-3; stage A(T+2); MFMA m0-3 ----
      #pragma unroll
      for (int n = 0; n < 4; n++) bfr[n] = rdB(s, n);
      #pragma unroll
      for (int m = 0; m < 4; m++) a0[m] = rdA(s, m);
      if (pf) stageT(Ab, 0, T + 2, s2);
      __builtin_amdgcn_s_setprio(1);
      #pragma unroll
      for (int m = 0; m < 4; m++)
        #pragma unroll
        for (int n = 0; n < 4; n++)
          acc[m][n] = __builtin_amdgcn_mfma_f32_16x16x32_bf16(a0[m], bfr[n], acc[m][n], 0, 0, 0);
      __builtin_amdgcn_s_setprio(0);
      __builtin_amdgcn_s_barrier();
    }
    { // ---- q1: read A m4-7; stage B(T+2); MFMA m4-7; tile-boundary wait ----
      #pragma unroll
      for (int m = 0; m < 4; m++) a1[m] = rdA(s, 4 + m);
      if (pf) stageT(Bb, 1, T + 2, s2);
      __builtin_amdgcn_s_setprio(1);
      #pragma unroll
      for (int m = 0; m < 4; m++)
        #pragma unroll
        for (int n = 0; n < 4; n++)
          acc[4 + m][n] = __builtin_amdgcn_mfma_f32_16x16x32_bf16(a1[m], bfr[n], acc[4 + m][n], 0, 0, 0);
      __builtin_amdgcn_s_setprio(0);
      if (pf)            asm volatile("s_waitcnt vmcnt(4)" ::: "memory");  // T+1 landed, T+2 in flight
      else if (T == 22)  asm volatile("s_waitcnt vmcnt(0)" ::: "memory");  // drain for last tile
      __builtin_amdgcn_s_barrier();
    }
    s  = (s  == 2) ? 0 : s  + 1;
    s2 = (s2 == 2) ? 0 : s2 + 1;
  }

  // epilogue: D layout col = lane&15, row = (lane>>4)*4 + reg; plain row-major store
  #pragma unroll
  for (int m = 0; m < 8; m++) {
    int rbase = bm * 256 + wm * 128 + m * 16 + (s16 << 2);
    #pragma unroll
    for (int n = 0; n < 4; n++) {
      int col = bn * 256 + wn * 64 + n * 16 + fr;
      float bcol = bias[col];
      float sc = (col < 768) ? 0.125f : 1.f;   // fold SCALE into q section
      f32x4 a = acc[m][n];
      #pragma unroll
      for (int r2 = 0; r2 < 4; r2++)
        qkv[(size_t)(rbase + r2) * 2304 + col] = (bf16_t)((a[r2] + bcol) * sc);
    }
  }
}

// ---------------- sparse windowed attention: one wave per (b, w, h), plain qkv layout ----------------
__global__ __launch_bounds__(64) void attn_kernel(const bf16_t* __restrict__ qkv,
                                                  bf16_t* __restrict__ ctx) {
  __shared__ float Ks[20][64];
  __shared__ float Vs[20][64];
  int id = blockIdx.x;               // ((b*128 + w)*12 + h)
  int h = id % 12;
  int bw = id / 12;
  int w = bw & 127, b = bw >> 7;
  int t = threadIdx.x;
  const int hc = h * 64;

  { // window-token K/V rows 0..15
    int j = t >> 2, dd = (t & 3) * 16;
    size_t row = (size_t)b * 2560 + w * 16 + j;
    const bf16_t* kp = qkv + row * 2304 + 768 + hc + dd;
    bf16x8 k0 = *(const bf16x8*)kp;
    bf16x8 k1 = *(const bf16x8*)(kp + 8);
    bf16x8 u0 = *(const bf16x8*)(kp + 768);
    bf16x8 u1 = *(const bf16x8*)(kp + 776);
    #pragma unroll
    for (int i = 0; i < 8; i++) {
      Ks[j][dd + i] = (float)k0[i]; Ks[j][dd + 8 + i] = (float)k1[i];
      Vs[j][dd + i] = (float)u0[i]; Vs[j][dd + 8 + i] = (float)u1[i];
    }
  }
  if (t < 16) { // carrier K/V rows 16..19
    int j = 16 + (t >> 2), dd = (t & 3) * 16;
    size_t row = (size_t)b * 2560 + 2048 + w * 4 + (t >> 2);
    const bf16_t* kp = qkv + row * 2304 + 768 + hc + dd;
    bf16x8 k0 = *(const bf16x8*)kp;
    bf16x8 k1 = *(const bf16x8*)(kp + 8);
    bf16x8 u0 = *(const bf16x8*)(kp + 768);
    bf16x8 u1 = *(const bf16x8*)(kp + 776);
    #pragma unroll
    for (int i = 0; i < 8; i++) {
      Ks[j][dd + i] = (float)k0[i]; Ks[j][dd + 8 + i] = (float)k1[i];
      Vs[j][dd + i] = (float)u0[i]; Vs[j][dd + 8 + i] = (float)u1[i];
    }
  }
  __syncthreads();

  int qi = t >> 2, c4 = t & 3, d0 = c4 * 16;
  float qreg[16];
  {
    const bf16_t* qp = qkv + ((size_t)b * 2560 + w * 16 + qi) * 2304 + hc + d0;
    bf16x8 q0 = *(const bf16x8*)qp;
    bf16x8 q1 = *(const bf16x8*)(qp + 8);
    #pragma unroll
    for (int i = 0; i < 8; i++) { qreg[i] = (float)q0[i]; qreg[8 + i] = (float)q1[i]; }
  }

  float pl[5];
  #pragma unroll
  for (int j = 0; j < 20; j++) {
    float s = 0.f;
    #pragma unroll
    for (int i = 0; i < 16; i++) s += qreg[i] * Ks[j][d0 + i];
    s += __shfl_xor(s, 1);
    s += __shfl_xor(s, 2);
    if ((j & 3) == c4) pl[j >> 2] = s;
  }
  float m = fmaxf(fmaxf(fmaxf(pl[0], pl[1]), fmaxf(pl[2], pl[3])), pl[4]);
  m = fmaxf(m, __shfl_xor(m, 1));
  m = fmaxf(m, __shfl_xor(m, 2));
  float sum = 0.f;
  #pragma unroll
  for (int i = 0; i < 5; i++) { pl[i] = __expf(pl[i] - m); sum += pl[i]; }
  sum += __shfl_xor(sum, 1);
  sum += __shfl_xor(sum, 2);
  float inv = 1.f / sum;

  float acc[16] = {};
  #pragma unroll
  for (int j = 0; j < 20; j++) {
    float pj = __shfl(pl[j >> 2], (qi << 2) | (j & 3));
    #pragma unroll
    for (int i = 0; i < 16; i++) acc[i] += pj * Vs[j][d0 + i];
  }

  bf16_t* cp = ctx + ((size_t)(b * 2048 + w * 16 + qi)) * 768 + hc + d0;
  #pragma unroll
  for (int i = 0; i < 16; i++) cp[i] = (bf16_t)(acc[i] * inv);
}

// ---------------- launch ----------------
extern "C" void kernel_launch(void* const* d_in, const int* in_sizes, int n_in,
                              void* d_out, int out_size, void* d_ws, size_t ws_size,
                              hipStream_t stream) {
  (void)in_sizes; (void)n_in; (void)out_size; (void)ws_size;
  const float* x      = (const float*)d_in[0];
  const float* W_qkv  = (const float*)d_in[1];
  const float* b_qkv  = (const float*)d_in[2];
  const float* W_car  = (const float*)d_in[3];
  const float* b_car  = (const float*)d_in[4];
  const float* W_proj = (const float*)d_in[5];
  const float* b_proj = (const float*)d_in[6];
  const float* gamma  = (const float*)d_in[7];
  const float* beta   = (const float*)d_in[8];
  float* out = (float*)d_out;

  char* ws = (char*)d_ws;
  bf16_t* wt_qkv  = (bf16_t*)(ws + OFF_WT_QKV);
  bf16_t* wt_car  = (bf16_t*)(ws + OFF_WT_CAR);
  bf16_t* wt_proj = (bf16_t*)(ws + OFF_WT_PROJ);
  bf16_t* wmean   = (bf16_t*)(ws + OFF_WMEAN);
  float*  carP    = (float*) (ws + OFF_CARP);
  bf16_t* ln      = (bf16_t*)(ws + OFF_LN);
  bf16_t* qkv     = (bf16_t*)(ws + OFF_QKV);
  bf16_t* ctx     = (bf16_t*)(ws + OFF_CTX);

  // 1. fused prep: weight transposes + window means
  prep_kernel<<<3136, 256, 0, stream>>>(W_qkv, W_car, W_proj, x,
                                        wt_qkv, wt_car, wt_proj, wmean);
  // 2. carrier GEMM, split-K=4 -> partials [4][256][768]
  gemm64_kernel<<<4 * 6 * 4, 256, 0, stream>>>(wmean, wt_car, nullptr, carP,
                                               4, 6, 192, 0);
  // 3. LayerNorm(combined) -> bf16  (sums car partials + b_car inline)
  ln_kernel<<<5120, 256, 0, stream>>>(x, carP, b_car, gamma, beta, ln);
  // 4. QKV projection: 256^2 3-slot-ring pipelined GEMM -> plain [5120][2304] bf16
  gemm256_qkv<<<180, 512, 0, stream>>>(ln, wt_qkv, b_qkv, qkv);
  // 5. sparse windowed attention -> ctx bf16
  attn_kernel<<<2 * 128 * 12, 64, 0, stream>>>(qkv, ctx);
  // 6. output projection -> d_out fp32
  gemm64_kernel<<<64 * 6, 256, 0, stream>>>(ctx, wt_proj, b_proj, out,
                                            64, 6, 768, 2);
}

// Round 8
// 79.537 us; speedup vs baseline: 1.3778x; 1.0257x over previous
//
#include <hip/hip_runtime.h>

typedef __bf16 bf16_t;
typedef __bf16 bf16x8 __attribute__((ext_vector_type(8)));
typedef float f32x4 __attribute__((ext_vector_type(4)));

#define GK 768   // inner K dim for every GEMM in this problem

// ---------------- workspace layout (bytes) ----------------
static constexpr size_t OFF_WT_QKV = 0;                                  // [2304][768] bf16
static constexpr size_t OFF_WT_CAR  = OFF_WT_QKV + (size_t)2304*768*2;   // [768][768] bf16
static constexpr size_t OFF_WT_PROJ = OFF_WT_CAR + (size_t)768*768*2;    // [768][768] bf16
static constexpr size_t OFF_WMEAN   = OFF_WT_PROJ + (size_t)768*768*2;   // [256][768] bf16
static constexpr size_t OFF_CARP    = OFF_WMEAN + (size_t)256*768*2;     // [4][256][768] f32 split-K partials
static constexpr size_t OFF_LN      = OFF_CARP + (size_t)4*256*768*4;    // [5120][768] bf16
static constexpr size_t OFF_QKV     = OFF_LN + (size_t)5120*768*2;       // [5120][2304] bf16 (q|k|v)
static constexpr size_t OFF_CTX     = OFF_QKV + (size_t)5120*2304*2;     // [2][2048][768] bf16

// ---------------- async global->LDS (16B per lane) ----------------
__device__ __forceinline__ void gload16(const bf16_t* g, bf16_t* lds_wave_base) {
  __builtin_amdgcn_global_load_lds(
      (const __attribute__((address_space(1))) unsigned int*)g,
      (__attribute__((address_space(3))) unsigned int*)lds_wave_base,
      16, 0, 0);
}

// ---------------- fused prep: 3 weight transposes (fp32->bf16, W[K][N]->Wt[N][K]) + window means ----------------
__global__ __launch_bounds__(256) void prep_kernel(const float* __restrict__ W_qkv,
                                                   const float* __restrict__ W_car,
                                                   const float* __restrict__ W_proj,
                                                   const float* __restrict__ x,
                                                   bf16_t* __restrict__ wt_qkv,
                                                   bf16_t* __restrict__ wt_car,
                                                   bf16_t* __restrict__ wt_proj,
                                                   bf16_t* __restrict__ wm) {
  int bid = blockIdx.x;
  if (bid < 2880) {
    __shared__ float tile[32][33];
    const float* W; bf16_t* Wt; int Ndim, kb, nb;
    if (bid < 1728) {
      W = W_qkv; Wt = wt_qkv; Ndim = 2304; kb = (bid % 24) * 32; nb = (bid / 24) * 32;
    } else if (bid < 2304) {
      int q = bid - 1728; W = W_car; Wt = wt_car; Ndim = 768; kb = (q % 24) * 32; nb = (q / 24) * 32;
    } else {
      int q = bid - 2304; W = W_proj; Wt = wt_proj; Ndim = 768; kb = (q % 24) * 32; nb = (q / 24) * 32;
    }
    int tx = threadIdx.x & 31, ty = threadIdx.x >> 5;   // ty in 0..7
    #pragma unroll
    for (int i = 0; i < 32; i += 8)
      tile[ty + i][tx] = W[(size_t)(kb + ty + i) * Ndim + nb + tx];
    __syncthreads();
    #pragma unroll
    for (int i = 0; i < 32; i += 8)
      Wt[(size_t)(nb + ty + i) * GK + kb + tx] = (bf16_t)tile[tx][ty + i];
  } else {
    int w = bid - 2880;            // 0..255  (b*128 + window)
    int b = w >> 7, ww = w & 127;
    const float* base = x + ((size_t)b * 2048 + (size_t)ww * 16) * 768;
    for (int d = threadIdx.x; d < 768; d += 256) {
      float s = 0.f;
      #pragma unroll
      for (int i = 0; i < 16; i++) s += base[(size_t)i * 768 + d];
      wm[(size_t)w * 768 + d] = (bf16_t)(s * (1.f / 16.f));
    }
  }
}

// ---------------- 64x128-tile bf16 MFMA GEMM, split-K (carrier GEMM only) ----------------
__global__ __launch_bounds__(256) void gemm64_kernel(const bf16_t* __restrict__ A,
                                                     const bf16_t* __restrict__ Bt,
                                                     float* __restrict__ outF,
                                                     int mB, int nB, int kspan) {
  __shared__ __align__(16) bf16_t As[64 * 32];
  __shared__ __align__(16) bf16_t Bs[128 * 32];
  int bid = blockIdx.x;
  int bm = bid % mB;
  int rest = bid / mB;
  int bn = rest % nB;
  int kz = rest / nB;
  int t = threadIdx.x, wid = t >> 6, lane = t & 63;
  int wm = wid >> 1, wn = wid & 1;
  int sr = t >> 2, sk = (t & 3) * 8;
  const bf16_t* gA = A + (size_t)(bm * 64 + sr) * GK + sk;
  const bf16_t* gB = Bt + (size_t)(bn * 128 + sr) * GK + sk;
  bf16_t* lA  = As + wid * 512;
  bf16_t* lB0 = Bs + wid * 512;
  bf16_t* lB1 = Bs + 2048 + wid * 512;
  int fr = lane & 15, fk = (lane >> 4) * 8;

  f32x4 acc[2][4] = {};
  int k0 = kz * kspan, kend = k0 + kspan;
  for (; k0 < kend; k0 += 32) {
    gload16(gA + k0,           lA);
    gload16(gB + k0,           lB0);
    gload16(gB + k0 + 64 * GK, lB1);
    __syncthreads();
    bf16x8 af[2], bfr[4];
    #pragma unroll
    for (int i = 0; i < 2; i++)
      af[i] = *(const bf16x8*)(As + (wm * 32 + i * 16 + fr) * 32 + fk);
    #pragma unroll
    for (int j = 0; j < 4; j++)
      bfr[j] = *(const bf16x8*)(Bs + (wn * 64 + j * 16 + fr) * 32 + fk);
    #pragma unroll
    for (int i = 0; i < 2; i++)
      #pragma unroll
      for (int j = 0; j < 4; j++)
        acc[i][j] = __builtin_amdgcn_mfma_f32_16x16x32_bf16(af[i], bfr[j], acc[i][j], 0, 0, 0);
    __syncthreads();
  }

  #pragma unroll
  for (int i = 0; i < 2; i++) {
    int rbase = bm * 64 + wm * 32 + i * 16 + ((lane >> 4) << 2);
    #pragma unroll
    for (int j = 0; j < 4; j++) {
      int col = bn * 128 + wn * 64 + j * 16 + (lane & 15);
      f32x4 a = acc[i][j];
      #pragma unroll
      for (int r = 0; r < 4; r++)
        outF[(size_t)kz * 196608 + (size_t)(rbase + r) * 768 + col] = a[r];
    }
  }
}

// ---------------- fused LayerNorm over "combined" rows -> bf16 ----------------
__global__ __launch_bounds__(256) void ln_kernel(const float* __restrict__ x,
                                                 const float* __restrict__ carP,
                                                 const float* __restrict__ b_car,
                                                 const float* __restrict__ gamma,
                                                 const float* __restrict__ beta,
                                                 bf16_t* __restrict__ out) {
  __shared__ float red[8];
  int row = blockIdx.x;                 // 0 .. 5119
  int b = row / 2560, n = row - b * 2560;
  int t = threadIdx.x;
  float v0, v1, v2;
  if (n < 2048) {
    const float* src = x + ((size_t)b * 2048 + n) * 768;
    v0 = src[t]; v1 = src[t + 256]; v2 = src[t + 512];
  } else {
    size_t ci = (size_t)(b * 128 + ((n - 2048) >> 2)) * 768;
    const float* p0 = carP + ci;
    const float* p1 = carP + ci + 196608;
    const float* p2 = carP + ci + 2 * 196608;
    const float* p3 = carP + ci + 3 * 196608;
    v0 = p0[t]       + p1[t]       + p2[t]       + p3[t]       + b_car[t];
    v1 = p0[t + 256] + p1[t + 256] + p2[t + 256] + p3[t + 256] + b_car[t + 256];
    v2 = p0[t + 512] + p1[t + 512] + p2[t + 512] + p3[t + 512] + b_car[t + 512];
  }
  float s = v0 + v1 + v2;
  float q = v0 * v0 + v1 * v1 + v2 * v2;
  #pragma unroll
  for (int o = 32; o > 0; o >>= 1) { s += __shfl_down(s, o); q += __shfl_down(q, o); }
  int wv = t >> 6;
  if ((t & 63) == 0) { red[wv] = s; red[4 + wv] = q; }
  __syncthreads();
  s = red[0] + red[1] + red[2] + red[3];
  q = red[4] + red[5] + red[6] + red[7];
  float mean = s * (1.f / 768.f);
  float var  = q * (1.f / 768.f) - mean * mean;
  float rstd = rsqrtf(var + 1e-5f);
  bf16_t* o0 = out + (size_t)row * 768;
  o0[t]       = (bf16_t)((v0 - mean) * rstd * gamma[t]       + beta[t]);
  o0[t + 256] = (bf16_t)((v1 - mean) * rstd * gamma[t + 256] + beta[t + 256]);
  o0[t + 512] = (bf16_t)((v2 - mean) * rstd * gamma[t + 512] + beta[t + 512]);
}

// ---------------- QKV GEMM: 256x256 tile, BK=32, 3-slot ring, counted vmcnt (R7, best) ----------------
__global__ __launch_bounds__(512, 1) void gemm256_qkv(const bf16_t* __restrict__ A,
                                                      const bf16_t* __restrict__ Bt,
                                                      const float* __restrict__ bias,
                                                      bf16_t* __restrict__ qkv) {
  __shared__ __align__(16) bf16_t smem[3][2][8192];   // [slot][A=0/B=1][r*32 + swz]

  // bijective XCD swizzle (m204): nwg=180, xcd 0..3 get 23 blocks, 4..7 get 22
  int xcd = blockIdx.x & 7, idx = blockIdx.x >> 3;
  int wgid = (xcd < 4 ? xcd * 23 : 92 + (xcd - 4) * 22) + idx;
  int bm = wgid / 9, bn = wgid % 9;

  int t = threadIdx.x;
  int w = t >> 6, lane = t & 63;
  int wm = w >> 2, wn = w & 3;          // wm: 128-row band, wn: 64-col band
  int fr = lane & 15, s16 = lane >> 4;

  const bf16_t* Ab = A  + (size_t)bm * 256 * GK;
  const bf16_t* Bb = Bt + (size_t)bn * 256 * GK;

  const int srow  = t >> 2;                              // 0..127
  const int skoff = (((t & 3) ^ ((t >> 3) & 3)) << 3);   // inverse-swizzled k-elem offset
  const int wbase = w * 512;                             // wave-uniform dest (HW adds lane*16B)

  auto stageT = [&](const bf16_t* src, int mat, int T, int s) {
    const bf16_t* g = src + (size_t)srow * GK + T * 32 + skoff;
    gload16(g,            &smem[s][mat][wbase]);
    gload16(g + 128 * GK, &smem[s][mat][4096 + wbase]);
  };
  auto rdA = [&](int s, int m) -> bf16x8 {
    int r = wm * 128 + m * 16 + fr;
    return *(const bf16x8*)(&smem[s][0][r * 32 + ((s16 ^ ((r >> 1) & 3)) << 3)]);
  };
  auto rdB = [&](int s, int n) -> bf16x8 {
    int r = wn * 64 + n * 16 + fr;
    return *(const bf16x8*)(&smem[s][1][r * 32 + ((s16 ^ ((r >> 1) & 3)) << 3)]);
  };

  f32x4 acc[8][4] = {};

  // prologue: tile 0 -> slot 0, tile 1 -> slot 1 (each wave: 8 loads)
  stageT(Ab, 0, 0, 0); stageT(Bb, 1, 0, 0);
  stageT(Ab, 0, 1, 1); stageT(Bb, 1, 1, 1);
  asm volatile("s_waitcnt vmcnt(4)" ::: "memory");   // tile 0 landed; tile 1's 4 in flight
  __builtin_amdgcn_s_barrier();

  int s = 0, s2 = 2;
  #pragma unroll 3
  for (int T = 0; T < 24; ++T) {
    const bool pf = (T <= 21);
    bf16x8 bfr[4], a0[4], a1[4];
    { // ---- q0: read B n0-3 + A m0-3; stage A(T+2); MFMA m0-3 ----
      #pragma unroll
      for (int n = 0; n < 4; n++) bfr[n] = rdB(s, n);
      #pragma unroll
      for (int m = 0; m < 4; m++) a0[m] = rdA(s, m);
      if (pf) stageT(Ab, 0, T + 2, s2);
      __builtin_amdgcn_s_setprio(1);
      #pragma unroll
      for (int m = 0; m < 4; m++)
        #pragma unroll
        for (int n = 0; n < 4; n++)
          acc[m][n] = __builtin_amdgcn_mfma_f32_16x16x32_bf16(a0[m], bfr[n], acc[m][n], 0, 0, 0);
      __builtin_amdgcn_s_setprio(0);
      __builtin_amdgcn_s_barrier();
    }
    { // ---- q1: read A m4-7; stage B(T+2); MFMA m4-7; tile-boundary wait ----
      #pragma unroll
      for (int m = 0; m < 4; m++) a1[m] = rdA(s, 4 + m);
      if (pf) stageT(Bb, 1, T + 2, s2);
      __builtin_amdgcn_s_setprio(1);
      #pragma unroll
      for (int m = 0; m < 4; m++)
        #pragma unroll
        for (int n = 0; n < 4; n++)
          acc[4 + m][n] = __builtin_amdgcn_mfma_f32_16x16x32_bf16(a1[m], bfr[n], acc[4 + m][n], 0, 0, 0);
      __builtin_amdgcn_s_setprio(0);
      if (pf)            asm volatile("s_waitcnt vmcnt(4)" ::: "memory");  // T+1 landed, T+2 in flight
      else if (T == 22)  asm volatile("s_waitcnt vmcnt(0)" ::: "memory");  // drain for last tile
      __builtin_amdgcn_s_barrier();
    }
    s  = (s  == 2) ? 0 : s  + 1;
    s2 = (s2 == 2) ? 0 : s2 + 1;
  }

  // epilogue: D layout col = lane&15, row = (lane>>4)*4 + reg; plain row-major store
  #pragma unroll
  for (int m = 0; m < 8; m++) {
    int rbase = bm * 256 + wm * 128 + m * 16 + (s16 << 2);
    #pragma unroll
    for (int n = 0; n < 4; n++) {
      int col = bn * 256 + wn * 64 + n * 16 + fr;
      float bcol = bias[col];
      float sc = (col < 768) ? 0.125f : 1.f;   // fold SCALE into q section
      f32x4 a = acc[m][n];
      #pragma unroll
      for (int r2 = 0; r2 < 4; r2++)
        qkv[(size_t)(rbase + r2) * 2304 + col] = (bf16_t)((a[r2] + bcol) * sc);
    }
  }
}

// ---------------- 128x128 proj GEMM (R4-verified body, fp32+bias epilogue) ----------------
__global__ __launch_bounds__(256) void gemm128_proj(const bf16_t* __restrict__ A,
                                                    const bf16_t* __restrict__ Bt,
                                                    const float* __restrict__ bias,
                                                    float* __restrict__ outF) {
  __shared__ __align__(16) bf16_t As[128 * 32];
  __shared__ __align__(16) bf16_t Bs[128 * 32];

  int bm = blockIdx.x % 32;           // M = 4096
  int bn = blockIdx.x / 32;           // N = 768 -> 6 tiles
  int t = threadIdx.x;
  int wid = t >> 6, lane = t & 63;
  int wm = wid >> 1, wn = wid & 1;

  int sr = t >> 2;
  int sk = (t & 3) * 8;
  const bf16_t* gA = A + ((size_t)(bm * 128 + sr)) * GK + sk;
  const bf16_t* gB = Bt + ((size_t)(bn * 128 + sr)) * GK + sk;
  bf16_t* lA0 = As + wid * 512;
  bf16_t* lA1 = As + 2048 + wid * 512;
  bf16_t* lB0 = Bs + wid * 512;
  bf16_t* lB1 = Bs + 2048 + wid * 512;

  int fr = lane & 15;
  int fk = (lane >> 4) * 8;

  f32x4 acc[4][4] = {};

  for (int k0 = 0; k0 < GK; k0 += 32) {
    gload16(gA + k0,            lA0);
    gload16(gA + k0 + 64 * GK,  lA1);
    gload16(gB + k0,            lB0);
    gload16(gB + k0 + 64 * GK,  lB1);
    __syncthreads();
    bf16x8 af[4], bfr[4];
    #pragma unroll
    for (int i = 0; i < 4; i++)
      af[i] = *(const bf16x8*)(As + (wm * 64 + i * 16 + fr) * 32 + fk);
    #pragma unroll
    for (int i = 0; i < 4; i++)
      bfr[i] = *(const bf16x8*)(Bs + (wn * 64 + i * 16 + fr) * 32 + fk);
    #pragma unroll
    for (int i = 0; i < 4; i++)
      #pragma unroll
      for (int j = 0; j < 4; j++)
        acc[i][j] = __builtin_amdgcn_mfma_f32_16x16x32_bf16(af[i], bfr[j], acc[i][j], 0, 0, 0);
    __syncthreads();
  }

  #pragma unroll
  for (int i = 0; i < 4; i++) {
    int rbase = bm * 128 + wm * 64 + i * 16 + ((lane >> 4) << 2);
    #pragma unroll
    for (int j = 0; j < 4; j++) {
      int col = bn * 128 + wn * 64 + j * 16 + (lane & 15);
      float bcol = bias[col];
      f32x4 a = acc[i][j];
      #pragma unroll
      for (int r = 0; r < 4; r++)
        outF[(size_t)(rbase + r) * 768 + col] = a[r] + bcol;
    }
  }
}

// ---------------- sparse windowed attention: 4 (b,w,h) units per 256-thr block ----------------
// One unit per wave; no cross-wave sharing -> no barriers (in-wave LDS RAW handled by lgkmcnt).
__global__ __launch_bounds__(256) void attn_kernel(const bf16_t* __restrict__ qkv,
                                                   bf16_t* __restrict__ ctx) {
  __shared__ float Ks[4][20][64];
  __shared__ float Vs[4][20][64];
  int tid = threadIdx.x;
  int wid = tid >> 6, lane = tid & 63;
  int id = blockIdx.x * 4 + wid;     // ((b*128 + w)*12 + h)
  int h = id % 12;
  int bw = id / 12;
  int w = bw & 127, b = bw >> 7;
  const int hc = h * 64;

  { // window-token K/V rows 0..15
    int j = lane >> 2, dd = (lane & 3) * 16;
    size_t row = (size_t)b * 2560 + w * 16 + j;
    const bf16_t* kp = qkv + row * 2304 + 768 + hc + dd;
    bf16x8 k0 = *(const bf16x8*)kp;
    bf16x8 k1 = *(const bf16x8*)(kp + 8);
    bf16x8 u0 = *(const bf16x8*)(kp + 768);
    bf16x8 u1 = *(const bf16x8*)(kp + 776);
    #pragma unroll
    for (int i = 0; i < 8; i++) {
      Ks[wid][j][dd + i] = (float)k0[i]; Ks[wid][j][dd + 8 + i] = (float)k1[i];
      Vs[wid][j][dd + i] = (float)u0[i]; Vs[wid][j][dd + 8 + i] = (float)u1[i];
    }
  }
  if (lane < 16) { // carrier K/V rows 16..19
    int j = 16 + (lane >> 2), dd = (lane & 3) * 16;
    size_t row = (size_t)b * 2560 + 2048 + w * 4 + (lane >> 2);
    const bf16_t* kp = qkv + row * 2304 + 768 + hc + dd;
    bf16x8 k0 = *(const bf16x8*)kp;
    bf16x8 k1 = *(const bf16x8*)(kp + 8);
    bf16x8 u0 = *(const bf16x8*)(kp + 768);
    bf16x8 u1 = *(const bf16x8*)(kp + 776);
    #pragma unroll
    for (int i = 0; i < 8; i++) {
      Ks[wid][j][dd + i] = (float)k0[i]; Ks[wid][j][dd + 8 + i] = (float)k1[i];
      Vs[wid][j][dd + i] = (float)u0[i]; Vs[wid][j][dd + 8 + i] = (float)u1[i];
    }
  }
  // no barrier: all consumers are in the producing wave

  int qi = lane >> 2, c4 = lane & 3, d0 = c4 * 16;
  float qreg[16];
  {
    const bf16_t* qp = qkv + ((size_t)b * 2560 + w * 16 + qi) * 2304 + hc + d0;
    bf16x8 q0 = *(const bf16x8*)qp;
    bf16x8 q1 = *(const bf16x8*)(qp + 8);
    #pragma unroll
    for (int i = 0; i < 8; i++) { qreg[i] = (float)q0[i]; qreg[8 + i] = (float)q1[i]; }
  }

  float pl[5];
  #pragma unroll
  for (int j = 0; j < 20; j++) {
    float s = 0.f;
    #pragma unroll
    for (int i = 0; i < 16; i++) s += qreg[i] * Ks[wid][j][d0 + i];
    s += __shfl_xor(s, 1);
    s += __shfl_xor(s, 2);
    if ((j & 3) == c4) pl[j >> 2] = s;
  }
  float m = fmaxf(fmaxf(fmaxf(pl[0], pl[1]), fmaxf(pl[2], pl[3])), pl[4]);
  m = fmaxf(m, __shfl_xor(m, 1));
  m = fmaxf(m, __shfl_xor(m, 2));
  float sum = 0.f;
  #pragma unroll
  for (int i = 0; i < 5; i++) { pl[i] = __expf(pl[i] - m); sum += pl[i]; }
  sum += __shfl_xor(sum, 1);
  sum += __shfl_xor(sum, 2);
  float inv = 1.f / sum;

  float acc[16] = {};
  #pragma unroll
  for (int j = 0; j < 20; j++) {
    float pj = __shfl(pl[j >> 2], (qi << 2) | (j & 3));
    #pragma unroll
    for (int i = 0; i < 16; i++) acc[i] += pj * Vs[wid][j][d0 + i];
  }

  bf16_t* cp = ctx + ((size_t)(b * 2048 + w * 16 + qi)) * 768 + hc + d0;
  #pragma unroll
  for (int i = 0; i < 16; i++) cp[i] = (bf16_t)(acc[i] * inv);
}

// ---------------- launch ----------------
extern "C" void kernel_launch(void* const* d_in, const int* in_sizes, int n_in,
                              void* d_out, int out_size, void* d_ws, size_t ws_size,
                              hipStream_t stream) {
  (void)in_sizes; (void)n_in; (void)out_size; (void)ws_size;
  const float* x      = (const float*)d_in[0];
  const float* W_qkv  = (const float*)d_in[1];
  const float* b_qkv  = (const float*)d_in[2];
  const float* W_car  = (const float*)d_in[3];
  const float* b_car  = (const float*)d_in[4];
  const float* W_proj = (const float*)d_in[5];
  const float* b_proj = (const float*)d_in[6];
  const float* gamma  = (const float*)d_in[7];
  const float* beta   = (const float*)d_in[8];
  float* out = (float*)d_out;

  char* ws = (char*)d_ws;
  bf16_t* wt_qkv  = (bf16_t*)(ws + OFF_WT_QKV);
  bf16_t* wt_car  = (bf16_t*)(ws + OFF_WT_CAR);
  bf16_t* wt_proj = (bf16_t*)(ws + OFF_WT_PROJ);
  bf16_t* wmean   = (bf16_t*)(ws + OFF_WMEAN);
  float*  carP    = (float*) (ws + OFF_CARP);
  bf16_t* ln      = (bf16_t*)(ws + OFF_LN);
  bf16_t* qkv     = (bf16_t*)(ws + OFF_QKV);
  bf16_t* ctx     = (bf16_t*)(ws + OFF_CTX);

  // 1. fused prep: weight transposes + window means
  prep_kernel<<<3136, 256, 0, stream>>>(W_qkv, W_car, W_proj, x,
                                        wt_qkv, wt_car, wt_proj, wmean);
  // 2. carrier GEMM, split-K=4 -> partials [4][256][768]
  gemm64_kernel<<<4 * 6 * 4, 256, 0, stream>>>(wmean, wt_car, carP, 4, 6, 192);
  // 3. LayerNorm(combined) -> bf16  (sums car partials + b_car inline)
  ln_kernel<<<5120, 256, 0, stream>>>(x, carP, b_car, gamma, beta, ln);
  // 4. QKV projection: 256^2 3-slot-ring pipelined GEMM -> plain [5120][2304] bf16
  gemm256_qkv<<<180, 512, 0, stream>>>(ln, wt_qkv, b_qkv, qkv);
  // 5. sparse windowed attention -> ctx bf16 (4 units per 256-thr block)
  attn_kernel<<<768, 256, 0, stream>>>(qkv, ctx);
  // 6. output projection -> d_out fp32 (128^2 tiles, 192 blocks)
  gemm128_proj<<<192, 256, 0, stream>>>(ctx, wt_proj, b_proj, out);
}